// Round 6
// baseline (518.494 us; speedup 1.0000x reference)
//
#include <hip/hip_runtime.h>

// ---------------------------------------------------------------------------
// LlamaAttention forward on MI355X (gfx950), bf16 MFMA pipeline.
// B=2, S=2048, H=2048, NH=32, KVH=8, D=64, G=4. Full (non-causal) softmax.
// Attention: GQA-shared K/V LDS staging, S^T = K*Q^T, no-max exp2 softmax
// (scores bounded; 0.125*log2e folded into Q), l-sum via ones-MFMA,
// DMA/compute overlapped barrier schedule.
// R6: 8-wave blocks (512 thr) = 4 heads x 2 q-subtiles share one K/V staging
//     -> grid 1024 = 4 blocks/CU of work, ALL co-resident (LDS 32KB x 4 =
//     128KB, VGPR 64/wave x 32 waves = full file) -> 100% static occupancy,
//     no quantization, K/V DMA traffic halved. launch_bounds(512,8) pins the
//     64-VGPR allocation R5 already achieved. s_setprio(1) around MFMA
//     clusters (T5). Extra barrier before epilogue (scratch spans Vs).
//     QKV RoPE epilogue: sincos from precomputed table (bit-identical ops,
//     computed in cast kernel) instead of 32 __sincosf per thread.
// P path fully in-register: cvt_pk_bf16 + v_permlane32_swap_b32 (K rows
// staged with bit2<->bit3 source permutation so post-swap fragments are in
// true key order).
// ---------------------------------------------------------------------------

typedef __bf16 bf16;
typedef __bf16 bf16x4_t __attribute__((ext_vector_type(4)));
typedef __bf16 bf16x8_t __attribute__((ext_vector_type(8)));
typedef float  f32x4_t  __attribute__((ext_vector_type(4)));
typedef unsigned int u32;
typedef unsigned int u32x4_t __attribute__((ext_vector_type(4)));

#define S_LEN 2048
#define HID   2048
#define NH    32
#define KVH   8
#define HD    64

__device__ __forceinline__ void async_copy16(const void* g, void* l) {
  __builtin_amdgcn_global_load_lds(
      (const __attribute__((address_space(1))) void*)g,
      (__attribute__((address_space(3))) void*)l, 16, 0, 0);
}

__device__ __forceinline__ u32 cvt_pk_bf16(float lo, float hi) {
  u32 r;
  asm("v_cvt_pk_bf16_f32 %0, %1, %2" : "=v"(r) : "v"(lo), "v"(hi));
  return r;
}

// After: a = {a[0:31], b[0:31]}, b = {a[32:63], b[32:63]}
__device__ __forceinline__ void permlane32_swap(u32& a, u32& b) {
  asm("v_permlane32_swap_b32 %0, %1" : "+v"(a), "+v"(b));
}

// ---------------- fp32 -> bf16 cast + RoPE cos/sin table -------------------
__global__ __launch_bounds__(256) void cast_bf16_kernel(
    const float* __restrict__ src, bf16* __restrict__ dst,
    float2* __restrict__ rope) {
  int gid = blockIdx.x * 256 + threadIdx.x;
  int i = gid * 4;
  float4 v = *(const float4*)(src + i);
  bf16x4_t o;
  o[0] = (bf16)v.x; o[1] = (bf16)v.y; o[2] = (bf16)v.z; o[3] = (bf16)v.w;
  *(bf16x4_t*)(dst + i) = o;
  if (gid < S_LEN * 32) {   // rope table: [s][i], i in 0..31
    int s = gid >> 5, fi = gid & 31;
    const float LE = 0.41524101186098285f; // log2(10000)/32
    float inv = __builtin_exp2f(-(float)fi * LE);
    float ang = (float)s * inv;
    float sv, cv;
    __sincosf(ang, &sv, &cv);
    rope[gid] = make_float2(cv, sv);
  }
}

// ---------------- fp32 [R][C] -> bf16 [C][dstStride] transpose -------------
__global__ __launch_bounds__(256) void wtrans_kernel(
    const float* __restrict__ src, bf16* __restrict__ dst, int C, int dstStride) {
  __shared__ float tile[32][33];
  int c0 = blockIdx.x * 32, r0 = blockIdx.y * 32;
  int t = threadIdx.x;
  int r = t >> 3, c4 = (t & 7) * 4;
  float4 v = *(const float4*)(src + (size_t)(r0 + r) * C + c0 + c4);
  tile[r][c4] = v.x; tile[r][c4 + 1] = v.y; tile[r][c4 + 2] = v.z; tile[r][c4 + 3] = v.w;
  __syncthreads();
  int cc = t >> 3, r4 = (t & 7) * 4;
  bf16x4_t o;
  o[0] = (bf16)tile[r4][cc];     o[1] = (bf16)tile[r4 + 1][cc];
  o[2] = (bf16)tile[r4 + 2][cc]; o[3] = (bf16)tile[r4 + 3][cc];
  *(bf16x4_t*)(dst + (size_t)(c0 + cc) * dstStride + r0 + r4) = o;
}

// ---------------- QKV GEMM (bf16 x bf16) + RoPE/scatter epilogue -----------
__global__ __launch_bounds__(256, 2) void qkv_gemm_rope(
    const bf16* __restrict__ A, const bf16* __restrict__ Bt,
    bf16* __restrict__ q_r, bf16* __restrict__ k_r, bf16* __restrict__ v_t,
    const float2* __restrict__ rope) {
  __shared__ char smem[32768];
  char* As = smem;
  char* Bs = smem + 16384;
  const int tid  = threadIdx.x;
  const int wid  = tid >> 6;
  const int lane = tid & 63;
  const int l15  = lane & 15;
  const int quad = lane >> 4;
  const int wm = wid >> 1, wn = wid & 1;
  const int bm = blockIdx.y * 128;
  const int bn = blockIdx.x * 128;
  const int K = 2048;

  f32x4_t acc[4][4] = {};

  for (int k0 = 0; k0 < K; k0 += 64) {
#pragma unroll
    for (int it = 0; it < 4; ++it) {
      int p = it * 256 + tid;
      int row = p >> 3;
      int j = (p & 7) ^ (row & 7);
      async_copy16(A + (size_t)(bm + row) * K + k0 + j * 8,
                   As + (size_t)(it * 256 + wid * 64) * 16);
      async_copy16(Bt + (size_t)(bn + row) * K + k0 + j * 8,
                   Bs + (size_t)(it * 256 + wid * 64) * 16);
    }
    __syncthreads();
#pragma unroll
    for (int kk = 0; kk < 64; kk += 32) {
      bf16x8_t af[4], bfr[4];
      int cbase = (kk >> 3) + quad;
#pragma unroll
      for (int mt = 0; mt < 4; ++mt) {
        int row = wm * 64 + mt * 16 + l15;
        af[mt] = *(const bf16x8_t*)(As + (size_t)(row * 8 + (cbase ^ (row & 7))) * 16);
      }
#pragma unroll
      for (int nt = 0; nt < 4; ++nt) {
        int row = wn * 64 + nt * 16 + l15;
        bfr[nt] = *(const bf16x8_t*)(Bs + (size_t)(row * 8 + (cbase ^ (row & 7))) * 16);
      }
#pragma unroll
      for (int mt = 0; mt < 4; ++mt)
#pragma unroll
        for (int nt = 0; nt < 4; ++nt)
          acc[mt][nt] = __builtin_amdgcn_mfma_f32_16x16x32_bf16(
              af[mt], bfr[nt], acc[mt][nt], 0, 0, 0);
    }
    __syncthreads();
  }

  const int cb = blockIdx.x * 2 + wn;
  const int rowbase = bm + wm * 64;
  const int bidx = bm >> 11;
  const float SC = 0.18033688011112043f; // 0.125 * log2(e), folded into Q

  if (cb < 40) {
    const bool isQ = (cb < 32);
    const float sc = isQ ? SC : 1.0f;
    bf16* base = isQ ? (q_r + (size_t)(bidx * NH + cb) * S_LEN * HD)
                     : (k_r + (size_t)(bidx * KVH + (cb - 32)) * S_LEN * HD);
#pragma unroll
    for (int nt = 0; nt < 2; ++nt) {
      int i = nt * 16 + l15;
#pragma unroll
      for (int mt = 0; mt < 4; ++mt)
#pragma unroll
        for (int r = 0; r < 4; ++r) {
          int row = rowbase + mt * 16 + quad * 4 + r;
          int s = row & 2047;
          float2 cs = rope[s * 32 + i];
          float x1 = acc[mt][nt][r], x2 = acc[mt][nt + 2][r];
          bf16* d = base + (size_t)s * HD;
          d[i]      = (bf16)((x1 * cs.x - x2 * cs.y) * sc);
          d[i + 32] = (bf16)((x2 * cs.x + x1 * cs.y) * sc);
        }
    }
  } else {
    const int kvh = cb - 40;
    bf16* base = v_t + (size_t)(bidx * KVH + kvh) * HD * S_LEN;
#pragma unroll
    for (int nt = 0; nt < 4; ++nt) {
      int d = nt * 16 + l15;
#pragma unroll
      for (int mt = 0; mt < 4; ++mt) {
        int s0 = (rowbase + mt * 16 + quad * 4) & 2047;
        bf16x4_t o;
        o[0] = (bf16)acc[mt][nt][0]; o[1] = (bf16)acc[mt][nt][1];
        o[2] = (bf16)acc[mt][nt][2]; o[3] = (bf16)acc[mt][nt][3];
        *(bf16x4_t*)(base + (size_t)d * S_LEN + s0) = o;
      }
    }
  }
}

// ---------------- bf16 GEMM: C[M][N] = A[M][K] * Bt[N][K]^T ----------------
template <typename OutT>
__global__ __launch_bounds__(256, 2) void gemm_bt(
    const bf16* __restrict__ A, const bf16* __restrict__ Bt,
    OutT* __restrict__ C, int N, int K) {
  __shared__ char smem[32768];
  char* As = smem;
  char* Bs = smem + 16384;
  const int tid  = threadIdx.x;
  const int wid  = tid >> 6;
  const int lane = tid & 63;
  const int l15  = lane & 15;
  const int quad = lane >> 4;
  const int wm = wid >> 1, wn = wid & 1;
  const int bm = blockIdx.y * 128;
  const int bn = blockIdx.x * 128;

  f32x4_t acc[4][4] = {};

  for (int k0 = 0; k0 < K; k0 += 64) {
#pragma unroll
    for (int it = 0; it < 4; ++it) {
      int p = it * 256 + tid;
      int row = p >> 3;
      int j = (p & 7) ^ (row & 7);
      async_copy16(A + (size_t)(bm + row) * K + k0 + j * 8,
                   As + (size_t)(it * 256 + wid * 64) * 16);
      async_copy16(Bt + (size_t)(bn + row) * K + k0 + j * 8,
                   Bs + (size_t)(it * 256 + wid * 64) * 16);
    }
    __syncthreads();
#pragma unroll
    for (int kk = 0; kk < 64; kk += 32) {
      bf16x8_t af[4], bfr[4];
      int cbase = (kk >> 3) + quad;
#pragma unroll
      for (int mt = 0; mt < 4; ++mt) {
        int row = wm * 64 + mt * 16 + l15;
        af[mt] = *(const bf16x8_t*)(As + (size_t)(row * 8 + (cbase ^ (row & 7))) * 16);
      }
#pragma unroll
      for (int nt = 0; nt < 4; ++nt) {
        int row = wn * 64 + nt * 16 + l15;
        bfr[nt] = *(const bf16x8_t*)(Bs + (size_t)(row * 8 + (cbase ^ (row & 7))) * 16);
      }
#pragma unroll
      for (int mt = 0; mt < 4; ++mt)
#pragma unroll
        for (int nt = 0; nt < 4; ++nt)
          acc[mt][nt] = __builtin_amdgcn_mfma_f32_16x16x32_bf16(
              af[mt], bfr[nt], acc[mt][nt], 0, 0, 0);
    }
    __syncthreads();
  }
#pragma unroll
  for (int mt = 0; mt < 4; ++mt)
#pragma unroll
    for (int nt = 0; nt < 4; ++nt)
#pragma unroll
      for (int r = 0; r < 4; ++r) {
        int row = bm + wm * 64 + mt * 16 + quad * 4 + r;
        int col = bn + wn * 64 + nt * 16 + l15;
        C[(size_t)row * N + col] = (OutT)acc[mt][nt][r];
      }
}

// ---------------- flash attention (GQA-shared, in-register P) --------------
// Block = 8 waves (512 thr) = 4 q-heads x 2 q-subtiles of one KV group;
// each wave: 16 queries. Grid (S/32=64, B*KVH=16) = 1024 blocks = 4/CU of
// work, all co-resident (LDS 4x32KB=128KB, 64 VGPR/wave x 32 waves).
// XCD-remapped: lin&7 owns KV groups {2*xcd, 2*xcd+1} -> hot K/V (1MB)
// stays in that XCD's 4MB L2.
// Barrier schedule: B1 drains K(kt) [DMA'd during prev PV]; V(kt) DMA
// overlaps S-phase + softmax; B2 drains V(kt); K(kt+1) DMA overlaps PV.
__global__ __launch_bounds__(512, 8) void attn_kernel(
    const bf16* __restrict__ q_r, const bf16* __restrict__ k_r,
    const bf16* __restrict__ v_t, bf16* __restrict__ attn) {
  __shared__ char smem[32768];
  char* Ks = smem;            // [key128][dim64], 3-bit row swizzle, 16KB
  char* Vs = smem + 16384;    // [dim64][key128], 4-bit row swizzle, 16KB
  const int tid = threadIdx.x;          // 0..511
  const int wid = tid >> 6;             // 0..7
  const int lane = tid & 63;
  const int l15 = lane & 15, quad = lane >> 4;

  // XCD-confined remap (bijective over 1024 blocks; dispatch is x-major
  // round-robin over 8 XCDs -> lin&7 == XCD id).
  const int lin = blockIdx.x + (blockIdx.y << 6);
  const int xcd = lin & 7;
  const int w = lin >> 3;                 // 0..127 within XCD
  const int blky = xcd * 2 + (w >> 6);    // b*KVH + kvh (2 groups per XCD)
  const int q0 = (w & 63) * 32 + (wid >> 2) * 16;

  const int b = blky >> 3, kvh = blky & 7;
  const int h = kvh * 4 + (wid & 3);      // this wave's q-head

  const bf16* Kg = k_r + (size_t)blky * S_LEN * HD;
  const bf16* Vg = v_t + (size_t)blky * HD * S_LEN;

  // Q fragments (B-operand: n=query=l15, k=dim=quad*8+j), pre-scaled.
  bf16x8_t qf0, qf1;
  {
    const bf16* qb = q_r + ((size_t)(b * NH + h) * S_LEN + q0 + l15) * HD;
    qf0 = *(const bf16x8_t*)(qb + quad * 8);
    qf1 = *(const bf16x8_t*)(qb + 32 + quad * 8);
  }
  bf16x8_t ones;
#pragma unroll
  for (int e = 0; e < 8; ++e) ones[e] = (bf16)1.0f;

  f32x4_t o_acc[4] = {};
  f32x4_t l_acc = {};

  // prologue: K(0) DMA (global source row bit2<->bit3 permuted)
#pragma unroll
  for (int it = 0; it < 2; ++it) {
    int p = it * 512 + tid;
    int row = p >> 3, j = (p & 7) ^ (row & 7);
    int gr = (row & ~12) | ((row & 4) << 1) | ((row & 8) >> 1);
    async_copy16(Kg + (size_t)gr * HD + j * 8,
                 Ks + (size_t)(it * 512 + wid * 64) * 16);
  }

  for (int kt = 0; kt < S_LEN / 128; ++kt) {
    __syncthreads();                     // B1: K(kt) landed; Vs free
#pragma unroll
    for (int it = 0; it < 2; ++it) {     // V(kt) DMA — overlaps S-phase
      int p = it * 512 + tid;
      int vrow = p >> 4, vj = (p & 15) ^ (vrow & 15);
      async_copy16(Vg + (size_t)vrow * S_LEN + kt * 128 + vj * 8,
                   Vs + (size_t)(it * 512 + wid * 64) * 16);
    }

    // S^T = K * Q^T for the 16-query tile; softmax+pack in registers.
    bf16x8_t pf[4];
    {
      f32x4_t sa[8];
#pragma unroll
      for (int t = 0; t < 8; ++t) sa[t] = f32x4_t{0.f, 0.f, 0.f, 0.f};
      __builtin_amdgcn_s_setprio(1);
#pragma unroll
      for (int t = 0; t < 8; ++t) {
        int row = t * 16 + l15;
        int s3 = l15 & 7;                // row&7 == l15&7 (16-aligned rows)
        bf16x8_t kf0 = *(const bf16x8_t*)(Ks + (size_t)(row * 8 + (quad ^ s3)) * 16);
        bf16x8_t kf1 = *(const bf16x8_t*)(Ks + (size_t)(row * 8 + ((4 + quad) ^ s3)) * 16);
        sa[t] = __builtin_amdgcn_mfma_f32_16x16x32_bf16(kf0, qf0, sa[t], 0, 0, 0);
        sa[t] = __builtin_amdgcn_mfma_f32_16x16x32_bf16(kf1, qf1, sa[t], 0, 0, 0);
      }
      __builtin_amdgcn_s_setprio(0);
      // exp2 + pack + permlane: build PV B-fragments in registers.
#pragma unroll
      for (int c = 0; c < 4; ++c) {
        u32 w0 = cvt_pk_bf16(__builtin_exp2f(sa[2 * c][0]),
                             __builtin_exp2f(sa[2 * c][1]));
        u32 w1 = cvt_pk_bf16(__builtin_exp2f(sa[2 * c][2]),
                             __builtin_exp2f(sa[2 * c][3]));
        u32 w2 = cvt_pk_bf16(__builtin_exp2f(sa[2 * c + 1][0]),
                             __builtin_exp2f(sa[2 * c + 1][1]));
        u32 w3 = cvt_pk_bf16(__builtin_exp2f(sa[2 * c + 1][2]),
                             __builtin_exp2f(sa[2 * c + 1][3]));
        permlane32_swap(w0, w2);         // w0 -> keys 8q'+{0,1}, w2 -> +{4,5}
        permlane32_swap(w1, w3);         // w1 -> keys 8q'+{2,3}, w3 -> +{6,7}
        u32x4_t pw;
        pw[0] = w0; pw[1] = w1; pw[2] = w2; pw[3] = w3;
        pf[c] = __builtin_bit_cast(bf16x8_t, pw);
      }
    }

    __syncthreads();                     // B2: V(kt) landed; Ks free

    if (kt < S_LEN / 128 - 1) {          // K(kt+1) DMA — overlaps PV
#pragma unroll
      for (int it = 0; it < 2; ++it) {
        int p = it * 512 + tid;
        int row = p >> 3, j = (p & 7) ^ (row & 7);
        int gr = (row & ~12) | ((row & 4) << 1) | ((row & 8) >> 1);
        async_copy16(Kg + (size_t)((kt + 1) * 128 + gr) * HD + j * 8,
                     Ks + (size_t)(it * 512 + wid * 64) * 16);
      }
    }

    // O^T += V^T * P^T ; l += ones * P^T (row-sum in matrix pipe).
    __builtin_amdgcn_s_setprio(1);
#pragma unroll
    for (int c = 0; c < 4; ++c) {
      l_acc = __builtin_amdgcn_mfma_f32_16x16x32_bf16(ones, pf[c], l_acc, 0, 0, 0);
#pragma unroll
      for (int nt = 0; nt < 4; ++nt) {
        int d = nt * 16 + l15;
        bf16x8_t vf = *(const bf16x8_t*)(Vs + d * 256 + (((4 * c + quad) ^ l15) * 16));
        o_acc[nt] = __builtin_amdgcn_mfma_f32_16x16x32_bf16(vf, pf[c], o_acc[nt], 0, 0, 0);
      }
    }
    __builtin_amdgcn_s_setprio(0);
  }

  __syncthreads();                       // all PV done; Ks+Vs reusable
  // finalize: every lane holds l for its query in l_acc[*] (all equal).
  char* Pw = smem + wid * 4096;          // 8 waves x 4KB spans Ks+Vs
  {
    float inv = 1.0f / l_acc[0];
    // O^T tile (cols=queries l15, rows=dims quad*4+r) -> Pw [16][72] transpose
#pragma unroll
    for (int nt = 0; nt < 4; ++nt) {
      bf16x4_t o;
      o[0] = (bf16)(o_acc[nt][0] * inv);
      o[1] = (bf16)(o_acc[nt][1] * inv);
      o[2] = (bf16)(o_acc[nt][2] * inv);
      o[3] = (bf16)(o_acc[nt][3] * inv);
      *(bf16x4_t*)(Pw + l15 * 144 + (nt * 16 + quad * 4) * 2) = o;
    }
    int row = lane >> 2, cc = lane & 3;
    bf16x8_t r0 = *(const bf16x8_t*)(Pw + row * 144 + cc * 32);
    bf16x8_t r1 = *(const bf16x8_t*)(Pw + row * 144 + cc * 32 + 16);
    int token = q0 + row;
    bf16* dst = attn + ((size_t)(b * S_LEN + token)) * HID + h * 64 + cc * 16;
    *(bf16x8_t*)dst = r0;
    *(bf16x8_t*)(dst + 8) = r1;
  }
}

// ---------------------------------------------------------------------------
extern "C" void kernel_launch(void* const* d_in, const int* in_sizes, int n_in,
                              void* d_out, int out_size, void* d_ws, size_t ws_size,
                              hipStream_t stream) {
  const float* x  = (const float*)d_in[0];
  const float* wq = (const float*)d_in[1];
  const float* wk = (const float*)d_in[2];
  const float* wv = (const float*)d_in[3];
  const float* wo = (const float*)d_in[4];
  float* out = (float*)d_out;
  char* ws = (char*)d_ws;

  // workspace layout (40 MiB, stream-ordered aliasing — proven):
  bf16* q_r    = (bf16*)(ws + 0);          // [0,16M)    QKV-epi .. attn
  bf16* k_r    = (bf16*)(ws + 16777216);   // [16M,20M)  QKV-epi .. attn
  bf16* v_t    = (bf16*)(ws + 20971520);   // [20M,24M)  QKV-epi .. attn
  bf16* wqkv_t = (bf16*)(ws + 25165824);   // [24M,36M)  dead after QKV GEMM
  bf16* attn   = (bf16*)(ws + 25165824);   // [24M,40M)  aliases wqkv_t
  bf16* wo_t   = (bf16*)(ws + 16777216);   // [16M,24M)  aliases k_r/v_t (after attn)
  float2* rope = (float2*)(ws + 37748736); // [36M,36.5M) gap after wqkv_t; dead before attn write
  bf16* x_b    = (bf16*)d_out;             // d_out as scratch (overwritten by O-GEMM)

  cast_bf16_kernel<<<8192, 256, 0, stream>>>(x, x_b, rope);
  wtrans_kernel<<<dim3(64, 64), 256, 0, stream>>>(wq, wqkv_t, 2048, 2048);
  wtrans_kernel<<<dim3(16, 64), 256, 0, stream>>>(wk, wqkv_t + (size_t)2048 * 2048, 512, 2048);
  wtrans_kernel<<<dim3(16, 64), 256, 0, stream>>>(wv, wqkv_t + (size_t)2560 * 2048, 512, 2048);

  qkv_gemm_rope<<<dim3(24, 32), 256, 0, stream>>>(x_b, wqkv_t, q_r, k_r, v_t, rope);
  attn_kernel<<<dim3(64, 16), 512, 0, stream>>>(q_r, k_r, v_t, attn);

  wtrans_kernel<<<dim3(64, 64), 256, 0, stream>>>(wo, wo_t, 2048, 2048);
  gemm_bt<float><<<dim3(16, 32), 256, 0, stream>>>(attn, wo_t, out, 2048, 2048);
}

// Round 8
// 313.062 us; speedup vs baseline: 1.6562x; 1.6562x over previous
//
#include <hip/hip_runtime.h>

// ---------------------------------------------------------------------------
// LlamaAttention forward on MI355X (gfx950), bf16 MFMA pipeline.
// B=2, S=2048, H=2048, NH=32, KVH=8, D=64, G=4. Full (non-causal) softmax.
// Attention: GQA-shared K/V LDS staging, S^T = K*Q^T, no-max exp2 softmax
// (scores bounded; 0.125*log2e folded into Q), l-sum via ones-MFMA,
// DMA/compute overlapped barrier schedule.
// R8 == R7 resubmitted (container infra failure, kernel never ran):
//     R6's 8-wave co-residency plan with the register bug fixed.
//     launch_bounds(512, 4) (cap 128) instead of (512, 8) (cap 64): R6's
//     hard 64-cap forced a 32/32 arch/acc split -> spill storm (FETCH 691MB,
//     VGPR_Count 32). With cap 128 the allocator lands at the natural 64
//     (proven by R5's identical per-wave code) -> 8 waves/SIMD feasible.
//     Block = 8 waves (512 thr) = 4 heads x 2 q-subtiles share one K/V
//     staging -> grid 1024 = 4 blocks/CU of work, ALL co-resident
//     (LDS 4x32KB=128KB, 64 VGPR x 32 waves) -> no backfill gaps, K/V DMA
//     traffic halved vs R5. s_setprio(1) around MFMA clusters (T5).
//     QKV RoPE epilogue reads precomputed sincos table (bit-identical ops).
// P path fully in-register: cvt_pk_bf16 + v_permlane32_swap_b32 (K rows
// staged with bit2<->bit3 source permutation so post-swap fragments are in
// true key order).
// ---------------------------------------------------------------------------

typedef __bf16 bf16;
typedef __bf16 bf16x4_t __attribute__((ext_vector_type(4)));
typedef __bf16 bf16x8_t __attribute__((ext_vector_type(8)));
typedef float  f32x4_t  __attribute__((ext_vector_type(4)));
typedef unsigned int u32;
typedef unsigned int u32x4_t __attribute__((ext_vector_type(4)));

#define S_LEN 2048
#define HID   2048
#define NH    32
#define KVH   8
#define HD    64

__device__ __forceinline__ void async_copy16(const void* g, void* l) {
  __builtin_amdgcn_global_load_lds(
      (const __attribute__((address_space(1))) void*)g,
      (__attribute__((address_space(3))) void*)l, 16, 0, 0);
}

__device__ __forceinline__ u32 cvt_pk_bf16(float lo, float hi) {
  u32 r;
  asm("v_cvt_pk_bf16_f32 %0, %1, %2" : "=v"(r) : "v"(lo), "v"(hi));
  return r;
}

// After: a = {a[0:31], b[0:31]}, b = {a[32:63], b[32:63]}
__device__ __forceinline__ void permlane32_swap(u32& a, u32& b) {
  asm("v_permlane32_swap_b32 %0, %1" : "+v"(a), "+v"(b));
}

// ---------------- fp32 -> bf16 cast + RoPE cos/sin table -------------------
__global__ __launch_bounds__(256) void cast_bf16_kernel(
    const float* __restrict__ src, bf16* __restrict__ dst,
    float2* __restrict__ rope) {
  int gid = blockIdx.x * 256 + threadIdx.x;
  int i = gid * 4;
  float4 v = *(const float4*)(src + i);
  bf16x4_t o;
  o[0] = (bf16)v.x; o[1] = (bf16)v.y; o[2] = (bf16)v.z; o[3] = (bf16)v.w;
  *(bf16x4_t*)(dst + i) = o;
  if (gid < S_LEN * 32) {   // rope table: [s][i], i in 0..31
    int s = gid >> 5, fi = gid & 31;
    const float LE = 0.41524101186098285f; // log2(10000)/32
    float inv = __builtin_exp2f(-(float)fi * LE);
    float ang = (float)s * inv;
    float sv, cv;
    __sincosf(ang, &sv, &cv);
    rope[gid] = make_float2(cv, sv);
  }
}

// ---------------- fp32 [R][C] -> bf16 [C][dstStride] transpose -------------
__global__ __launch_bounds__(256) void wtrans_kernel(
    const float* __restrict__ src, bf16* __restrict__ dst, int C, int dstStride) {
  __shared__ float tile[32][33];
  int c0 = blockIdx.x * 32, r0 = blockIdx.y * 32;
  int t = threadIdx.x;
  int r = t >> 3, c4 = (t & 7) * 4;
  float4 v = *(const float4*)(src + (size_t)(r0 + r) * C + c0 + c4);
  tile[r][c4] = v.x; tile[r][c4 + 1] = v.y; tile[r][c4 + 2] = v.z; tile[r][c4 + 3] = v.w;
  __syncthreads();
  int cc = t >> 3, r4 = (t & 7) * 4;
  bf16x4_t o;
  o[0] = (bf16)tile[r4][cc];     o[1] = (bf16)tile[r4 + 1][cc];
  o[2] = (bf16)tile[r4 + 2][cc]; o[3] = (bf16)tile[r4 + 3][cc];
  *(bf16x4_t*)(dst + (size_t)(c0 + cc) * dstStride + r0 + r4) = o;
}

// ---------------- QKV GEMM (bf16 x bf16) + RoPE/scatter epilogue -----------
__global__ __launch_bounds__(256, 2) void qkv_gemm_rope(
    const bf16* __restrict__ A, const bf16* __restrict__ Bt,
    bf16* __restrict__ q_r, bf16* __restrict__ k_r, bf16* __restrict__ v_t,
    const float2* __restrict__ rope) {
  __shared__ char smem[32768];
  char* As = smem;
  char* Bs = smem + 16384;
  const int tid  = threadIdx.x;
  const int wid  = tid >> 6;
  const int lane = tid & 63;
  const int l15  = lane & 15;
  const int quad = lane >> 4;
  const int wm = wid >> 1, wn = wid & 1;
  const int bm = blockIdx.y * 128;
  const int bn = blockIdx.x * 128;
  const int K = 2048;

  f32x4_t acc[4][4] = {};

  for (int k0 = 0; k0 < K; k0 += 64) {
#pragma unroll
    for (int it = 0; it < 4; ++it) {
      int p = it * 256 + tid;
      int row = p >> 3;
      int j = (p & 7) ^ (row & 7);
      async_copy16(A + (size_t)(bm + row) * K + k0 + j * 8,
                   As + (size_t)(it * 256 + wid * 64) * 16);
      async_copy16(Bt + (size_t)(bn + row) * K + k0 + j * 8,
                   Bs + (size_t)(it * 256 + wid * 64) * 16);
    }
    __syncthreads();
#pragma unroll
    for (int kk = 0; kk < 64; kk += 32) {
      bf16x8_t af[4], bfr[4];
      int cbase = (kk >> 3) + quad;
#pragma unroll
      for (int mt = 0; mt < 4; ++mt) {
        int row = wm * 64 + mt * 16 + l15;
        af[mt] = *(const bf16x8_t*)(As + (size_t)(row * 8 + (cbase ^ (row & 7))) * 16);
      }
#pragma unroll
      for (int nt = 0; nt < 4; ++nt) {
        int row = wn * 64 + nt * 16 + l15;
        bfr[nt] = *(const bf16x8_t*)(Bs + (size_t)(row * 8 + (cbase ^ (row & 7))) * 16);
      }
#pragma unroll
      for (int mt = 0; mt < 4; ++mt)
#pragma unroll
        for (int nt = 0; nt < 4; ++nt)
          acc[mt][nt] = __builtin_amdgcn_mfma_f32_16x16x32_bf16(
              af[mt], bfr[nt], acc[mt][nt], 0, 0, 0);
    }
    __syncthreads();
  }

  const int cb = blockIdx.x * 2 + wn;
  const int rowbase = bm + wm * 64;
  const int bidx = bm >> 11;
  const float SC = 0.18033688011112043f; // 0.125 * log2(e), folded into Q

  if (cb < 40) {
    const bool isQ = (cb < 32);
    const float sc = isQ ? SC : 1.0f;
    bf16* base = isQ ? (q_r + (size_t)(bidx * NH + cb) * S_LEN * HD)
                     : (k_r + (size_t)(bidx * KVH + (cb - 32)) * S_LEN * HD);
#pragma unroll
    for (int nt = 0; nt < 2; ++nt) {
      int i = nt * 16 + l15;
#pragma unroll
      for (int mt = 0; mt < 4; ++mt)
#pragma unroll
        for (int r = 0; r < 4; ++r) {
          int row = rowbase + mt * 16 + quad * 4 + r;
          int s = row & 2047;
          float2 cs = rope[s * 32 + i];
          float x1 = acc[mt][nt][r], x2 = acc[mt][nt + 2][r];
          bf16* d = base + (size_t)s * HD;
          d[i]      = (bf16)((x1 * cs.x - x2 * cs.y) * sc);
          d[i + 32] = (bf16)((x2 * cs.x + x1 * cs.y) * sc);
        }
    }
  } else {
    const int kvh = cb - 40;
    bf16* base = v_t + (size_t)(bidx * KVH + kvh) * HD * S_LEN;
#pragma unroll
    for (int nt = 0; nt < 4; ++nt) {
      int d = nt * 16 + l15;
#pragma unroll
      for (int mt = 0; mt < 4; ++mt) {
        int s0 = (rowbase + mt * 16 + quad * 4) & 2047;
        bf16x4_t o;
        o[0] = (bf16)acc[mt][nt][0]; o[1] = (bf16)acc[mt][nt][1];
        o[2] = (bf16)acc[mt][nt][2]; o[3] = (bf16)acc[mt][nt][3];
        *(bf16x4_t*)(base + (size_t)d * S_LEN + s0) = o;
      }
    }
  }
}

// ---------------- bf16 GEMM: C[M][N] = A[M][K] * Bt[N][K]^T ----------------
template <typename OutT>
__global__ __launch_bounds__(256, 2) void gemm_bt(
    const bf16* __restrict__ A, const bf16* __restrict__ Bt,
    OutT* __restrict__ C, int N, int K) {
  __shared__ char smem[32768];
  char* As = smem;
  char* Bs = smem + 16384;
  const int tid  = threadIdx.x;
  const int wid  = tid >> 6;
  const int lane = tid & 63;
  const int l15  = lane & 15;
  const int quad = lane >> 4;
  const int wm = wid >> 1, wn = wid & 1;
  const int bm = blockIdx.y * 128;
  const int bn = blockIdx.x * 128;

  f32x4_t acc[4][4] = {};

  for (int k0 = 0; k0 < K; k0 += 64) {
#pragma unroll
    for (int it = 0; it < 4; ++it) {
      int p = it * 256 + tid;
      int row = p >> 3;
      int j = (p & 7) ^ (row & 7);
      async_copy16(A + (size_t)(bm + row) * K + k0 + j * 8,
                   As + (size_t)(it * 256 + wid * 64) * 16);
      async_copy16(Bt + (size_t)(bn + row) * K + k0 + j * 8,
                   Bs + (size_t)(it * 256 + wid * 64) * 16);
    }
    __syncthreads();
#pragma unroll
    for (int kk = 0; kk < 64; kk += 32) {
      bf16x8_t af[4], bfr[4];
      int cbase = (kk >> 3) + quad;
#pragma unroll
      for (int mt = 0; mt < 4; ++mt) {
        int row = wm * 64 + mt * 16 + l15;
        af[mt] = *(const bf16x8_t*)(As + (size_t)(row * 8 + (cbase ^ (row & 7))) * 16);
      }
#pragma unroll
      for (int nt = 0; nt < 4; ++nt) {
        int row = wn * 64 + nt * 16 + l15;
        bfr[nt] = *(const bf16x8_t*)(Bs + (size_t)(row * 8 + (cbase ^ (row & 7))) * 16);
      }
#pragma unroll
      for (int mt = 0; mt < 4; ++mt)
#pragma unroll
        for (int nt = 0; nt < 4; ++nt)
          acc[mt][nt] = __builtin_amdgcn_mfma_f32_16x16x32_bf16(
              af[mt], bfr[nt], acc[mt][nt], 0, 0, 0);
    }
    __syncthreads();
  }
#pragma unroll
  for (int mt = 0; mt < 4; ++mt)
#pragma unroll
    for (int nt = 0; nt < 4; ++nt)
#pragma unroll
      for (int r = 0; r < 4; ++r) {
        int row = bm + wm * 64 + mt * 16 + quad * 4 + r;
        int col = bn + wn * 64 + nt * 16 + l15;
        C[(size_t)row * N + col] = (OutT)acc[mt][nt][r];
      }
}

// ---------------- flash attention (GQA-shared, in-register P) --------------
// Block = 8 waves (512 thr) = 4 q-heads x 2 q-subtiles of one KV group;
// each wave: 16 queries. Grid (S/32=64, B*KVH=16) = 1024 blocks = 4/CU of
// work, all co-resident (LDS 4x32KB=128KB, ~64 VGPR/wave x 32 waves).
// XCD-remapped: lin&7 owns KV groups {2*xcd, 2*xcd+1} -> hot K/V (1MB)
// stays in that XCD's 4MB L2.
// Barrier schedule: B1 drains K(kt) [DMA'd during prev PV]; V(kt) DMA
// overlaps S-phase + softmax; B2 drains V(kt); K(kt+1) DMA overlaps PV.
__global__ __launch_bounds__(512, 4) void attn_kernel(
    const bf16* __restrict__ q_r, const bf16* __restrict__ k_r,
    const bf16* __restrict__ v_t, bf16* __restrict__ attn) {
  __shared__ char smem[32768];
  char* Ks = smem;            // [key128][dim64], 3-bit row swizzle, 16KB
  char* Vs = smem + 16384;    // [dim64][key128], 4-bit row swizzle, 16KB
  const int tid = threadIdx.x;          // 0..511
  const int wid = tid >> 6;             // 0..7
  const int lane = tid & 63;
  const int l15 = lane & 15, quad = lane >> 4;

  // XCD-confined remap (bijective over 1024 blocks; dispatch is x-major
  // round-robin over 8 XCDs -> lin&7 == XCD id).
  const int lin = blockIdx.x + (blockIdx.y << 6);
  const int xcd = lin & 7;
  const int w = lin >> 3;                 // 0..127 within XCD
  const int blky = xcd * 2 + (w >> 6);    // b*KVH + kvh (2 groups per XCD)
  const int q0 = (w & 63) * 32 + (wid >> 2) * 16;

  const int b = blky >> 3, kvh = blky & 7;
  const int h = kvh * 4 + (wid & 3);      // this wave's q-head

  const bf16* Kg = k_r + (size_t)blky * S_LEN * HD;
  const bf16* Vg = v_t + (size_t)blky * HD * S_LEN;

  // Q fragments (B-operand: n=query=l15, k=dim=quad*8+j), pre-scaled.
  bf16x8_t qf0, qf1;
  {
    const bf16* qb = q_r + ((size_t)(b * NH + h) * S_LEN + q0 + l15) * HD;
    qf0 = *(const bf16x8_t*)(qb + quad * 8);
    qf1 = *(const bf16x8_t*)(qb + 32 + quad * 8);
  }
  bf16x8_t ones;
#pragma unroll
  for (int e = 0; e < 8; ++e) ones[e] = (bf16)1.0f;

  f32x4_t o_acc[4] = {};
  f32x4_t l_acc = {};

  // prologue: K(0) DMA (global source row bit2<->bit3 permuted)
#pragma unroll
  for (int it = 0; it < 2; ++it) {
    int p = it * 512 + tid;
    int row = p >> 3, j = (p & 7) ^ (row & 7);
    int gr = (row & ~12) | ((row & 4) << 1) | ((row & 8) >> 1);
    async_copy16(Kg + (size_t)gr * HD + j * 8,
                 Ks + (size_t)(it * 512 + wid * 64) * 16);
  }

  for (int kt = 0; kt < S_LEN / 128; ++kt) {
    __syncthreads();                     // B1: K(kt) landed; Vs free
#pragma unroll
    for (int it = 0; it < 2; ++it) {     // V(kt) DMA — overlaps S-phase
      int p = it * 512 + tid;
      int vrow = p >> 4, vj = (p & 15) ^ (vrow & 15);
      async_copy16(Vg + (size_t)vrow * S_LEN + kt * 128 + vj * 8,
                   Vs + (size_t)(it * 512 + wid * 64) * 16);
    }

    // S^T = K * Q^T for the 16-query tile; softmax+pack in registers.
    bf16x8_t pf[4];
    {
      f32x4_t sa[8];
#pragma unroll
      for (int t = 0; t < 8; ++t) sa[t] = f32x4_t{0.f, 0.f, 0.f, 0.f};
      __builtin_amdgcn_s_setprio(1);
#pragma unroll
      for (int t = 0; t < 8; ++t) {
        int row = t * 16 + l15;
        int s3 = l15 & 7;                // row&7 == l15&7 (16-aligned rows)
        bf16x8_t kf0 = *(const bf16x8_t*)(Ks + (size_t)(row * 8 + (quad ^ s3)) * 16);
        bf16x8_t kf1 = *(const bf16x8_t*)(Ks + (size_t)(row * 8 + ((4 + quad) ^ s3)) * 16);
        sa[t] = __builtin_amdgcn_mfma_f32_16x16x32_bf16(kf0, qf0, sa[t], 0, 0, 0);
        sa[t] = __builtin_amdgcn_mfma_f32_16x16x32_bf16(kf1, qf1, sa[t], 0, 0, 0);
      }
      __builtin_amdgcn_s_setprio(0);
      // exp2 + pack + permlane: build PV B-fragments in registers.
#pragma unroll
      for (int c = 0; c < 4; ++c) {
        u32 w0 = cvt_pk_bf16(__builtin_exp2f(sa[2 * c][0]),
                             __builtin_exp2f(sa[2 * c][1]));
        u32 w1 = cvt_pk_bf16(__builtin_exp2f(sa[2 * c][2]),
                             __builtin_exp2f(sa[2 * c][3]));
        u32 w2 = cvt_pk_bf16(__builtin_exp2f(sa[2 * c + 1][0]),
                             __builtin_exp2f(sa[2 * c + 1][1]));
        u32 w3 = cvt_pk_bf16(__builtin_exp2f(sa[2 * c + 1][2]),
                             __builtin_exp2f(sa[2 * c + 1][3]));
        permlane32_swap(w0, w2);         // w0 -> keys 8q'+{0,1}, w2 -> +{4,5}
        permlane32_swap(w1, w3);         // w1 -> keys 8q'+{2,3}, w3 -> +{6,7}
        u32x4_t pw;
        pw[0] = w0; pw[1] = w1; pw[2] = w2; pw[3] = w3;
        pf[c] = __builtin_bit_cast(bf16x8_t, pw);
      }
    }

    __syncthreads();                     // B2: V(kt) landed; Ks free

    if (kt < S_LEN / 128 - 1) {          // K(kt+1) DMA — overlaps PV
#pragma unroll
      for (int it = 0; it < 2; ++it) {
        int p = it * 512 + tid;
        int row = p >> 3, j = (p & 7) ^ (row & 7);
        int gr = (row & ~12) | ((row & 4) << 1) | ((row & 8) >> 1);
        async_copy16(Kg + (size_t)((kt + 1) * 128 + gr) * HD + j * 8,
                     Ks + (size_t)(it * 512 + wid * 64) * 16);
      }
    }

    // O^T += V^T * P^T ; l += ones * P^T (row-sum in matrix pipe).
    __builtin_amdgcn_s_setprio(1);
#pragma unroll
    for (int c = 0; c < 4; ++c) {
      l_acc = __builtin_amdgcn_mfma_f32_16x16x32_bf16(ones, pf[c], l_acc, 0, 0, 0);
#pragma unroll
      for (int nt = 0; nt < 4; ++nt) {
        int d = nt * 16 + l15;
        bf16x8_t vf = *(const bf16x8_t*)(Vs + d * 256 + (((4 * c + quad) ^ l15) * 16));
        o_acc[nt] = __builtin_amdgcn_mfma_f32_16x16x32_bf16(vf, pf[c], o_acc[nt], 0, 0, 0);
      }
    }
    __builtin_amdgcn_s_setprio(0);
  }

  __syncthreads();                       // all PV done; Ks+Vs reusable
  // finalize: every lane holds l for its query in l_acc[*] (all equal).
  char* Pw = smem + wid * 4096;          // 8 waves x 4KB spans Ks+Vs
  {
    float inv = 1.0f / l_acc[0];
    // O^T tile (cols=queries l15, rows=dims quad*4+r) -> Pw [16][72] transpose
#pragma unroll
    for (int nt = 0; nt < 4; ++nt) {
      bf16x4_t o;
      o[0] = (bf16)(o_acc[nt][0] * inv);
      o[1] = (bf16)(o_acc[nt][1] * inv);
      o[2] = (bf16)(o_acc[nt][2] * inv);
      o[3] = (bf16)(o_acc[nt][3] * inv);
      *(bf16x4_t*)(Pw + l15 * 144 + (nt * 16 + quad * 4) * 2) = o;
    }
    int row = lane >> 2, cc = lane & 3;
    bf16x8_t r0 = *(const bf16x8_t*)(Pw + row * 144 + cc * 32);
    bf16x8_t r1 = *(const bf16x8_t*)(Pw + row * 144 + cc * 32 + 16);
    int token = q0 + row;
    bf16* dst = attn + ((size_t)(b * S_LEN + token)) * HID + h * 64 + cc * 16;
    *(bf16x8_t*)dst = r0;
    *(bf16x8_t*)(dst + 8) = r1;
  }
}

// ---------------------------------------------------------------------------
extern "C" void kernel_launch(void* const* d_in, const int* in_sizes, int n_in,
                              void* d_out, int out_size, void* d_ws, size_t ws_size,
                              hipStream_t stream) {
  const float* x  = (const float*)d_in[0];
  const float* wq = (const float*)d_in[1];
  const float* wk = (const float*)d_in[2];
  const float* wv = (const float*)d_in[3];
  const float* wo = (const float*)d_in[4];
  float* out = (float*)d_out;
  char* ws = (char*)d_ws;

  // workspace layout (40 MiB, stream-ordered aliasing — proven):
  bf16* q_r    = (bf16*)(ws + 0);          // [0,16M)    QKV-epi .. attn
  bf16* k_r    = (bf16*)(ws + 16777216);   // [16M,20M)  QKV-epi .. attn
  bf16* v_t    = (bf16*)(ws + 20971520);   // [20M,24M)  QKV-epi .. attn
  bf16* wqkv_t = (bf16*)(ws + 25165824);   // [24M,36M)  dead after QKV GEMM
  bf16* attn   = (bf16*)(ws + 25165824);   // [24M,40M)  aliases wqkv_t
  bf16* wo_t   = (bf16*)(ws + 16777216);   // [16M,24M)  aliases k_r/v_t (after attn)
  float2* rope = (float2*)(ws + 37748736); // [36M,36.5M) written by cast, read by
                                           // qkv_gemm_rope, dead before attn writes
  bf16* x_b    = (bf16*)d_out;             // d_out as scratch (overwritten by O-GEMM)

  cast_bf16_kernel<<<8192, 256, 0, stream>>>(x, x_b, rope);
  wtrans_kernel<<<dim3(64, 64), 256, 0, stream>>>(wq, wqkv_t, 2048, 2048);
  wtrans_kernel<<<dim3(16, 64), 256, 0, stream>>>(wk, wqkv_t + (size_t)2048 * 2048, 512, 2048);
  wtrans_kernel<<<dim3(16, 64), 256, 0, stream>>>(wv, wqkv_t + (size_t)2560 * 2048, 512, 2048);

  qkv_gemm_rope<<<dim3(24, 32), 256, 0, stream>>>(x_b, wqkv_t, q_r, k_r, v_t, rope);
  attn_kernel<<<dim3(64, 16), 512, 0, stream>>>(q_r, k_r, v_t, attn);

  wtrans_kernel<<<dim3(64, 64), 256, 0, stream>>>(wo, wo_t, 2048, 2048);
  gemm_bt<float><<<dim3(16, 32), 256, 0, stream>>>(attn, wo_t, out, 2048, 2048);
}

// Round 9
// 305.565 us; speedup vs baseline: 1.6968x; 1.0245x over previous
//
#include <hip/hip_runtime.h>

// ---------------------------------------------------------------------------
// LlamaAttention forward on MI355X (gfx950), bf16 MFMA pipeline.
// B=2, S=2048, H=2048, NH=32, KVH=8, D=64, G=4. Full (non-causal) softmax.
// R9: attn kernel frozen at R8 (108 us, register-wall at ~124 unified regs).
//     New: (a) XCD-confined chunked-bijective block swizzle in BOTH GEMMs
//     (T1; A-panels become L2-resident per XCD, as proven for attn K/V);
//     (b) wq/wk/wv transposes fused into ONE launch (8 -> 6 dispatches).
// P path fully in-register: cvt_pk_bf16 + v_permlane32_swap_b32 (K rows
// staged with bit2<->bit3 source permutation so post-swap fragments are in
// true key order).
// ---------------------------------------------------------------------------

typedef __bf16 bf16;
typedef __bf16 bf16x4_t __attribute__((ext_vector_type(4)));
typedef __bf16 bf16x8_t __attribute__((ext_vector_type(8)));
typedef float  f32x4_t  __attribute__((ext_vector_type(4)));
typedef unsigned int u32;
typedef unsigned int u32x4_t __attribute__((ext_vector_type(4)));

#define S_LEN 2048
#define HID   2048
#define NH    32
#define KVH   8
#define HD    64

__device__ __forceinline__ void async_copy16(const void* g, void* l) {
  __builtin_amdgcn_global_load_lds(
      (const __attribute__((address_space(1))) void*)g,
      (__attribute__((address_space(3))) void*)l, 16, 0, 0);
}

__device__ __forceinline__ u32 cvt_pk_bf16(float lo, float hi) {
  u32 r;
  asm("v_cvt_pk_bf16_f32 %0, %1, %2" : "=v"(r) : "v"(lo), "v"(hi));
  return r;
}

// After: a = {a[0:31], b[0:31]}, b = {a[32:63], b[32:63]}
__device__ __forceinline__ void permlane32_swap(u32& a, u32& b) {
  asm("v_permlane32_swap_b32 %0, %1" : "+v"(a), "+v"(b));
}

// ---------------- fp32 -> bf16 cast + RoPE cos/sin table -------------------
__global__ __launch_bounds__(256) void cast_bf16_kernel(
    const float* __restrict__ src, bf16* __restrict__ dst,
    float2* __restrict__ rope) {
  int gid = blockIdx.x * 256 + threadIdx.x;
  int i = gid * 4;
  float4 v = *(const float4*)(src + i);
  bf16x4_t o;
  o[0] = (bf16)v.x; o[1] = (bf16)v.y; o[2] = (bf16)v.z; o[3] = (bf16)v.w;
  *(bf16x4_t*)(dst + i) = o;
  if (gid < S_LEN * 32) {   // rope table: [s][i], i in 0..31
    int s = gid >> 5, fi = gid & 31;
    const float LE = 0.41524101186098285f; // log2(10000)/32
    float inv = __builtin_exp2f(-(float)fi * LE);
    float ang = (float)s * inv;
    float sv, cv;
    __sincosf(ang, &sv, &cv);
    rope[gid] = make_float2(cv, sv);
  }
}

// ---------------- fp32 [R][C] -> bf16 [C][2048] transpose, fused wq/wk/wv --
// grid (96, 64): bx<64 -> wq (C=2048); 64..79 -> wk (C=512); 80..95 -> wv.
// Branch is block-uniform (no divergence).
__global__ __launch_bounds__(256) void wtrans3_kernel(
    const float* __restrict__ wq, const float* __restrict__ wk,
    const float* __restrict__ wv, bf16* __restrict__ dst) {
  __shared__ float tile[32][33];
  int bx = blockIdx.x;
  const float* src;
  int C;
  bf16* d0;
  if (bx < 64)      { src = wq; C = 2048; d0 = dst; }
  else if (bx < 80) { src = wk; C = 512;  d0 = dst + (size_t)2048 * 2048; bx -= 64; }
  else              { src = wv; C = 512;  d0 = dst + (size_t)2560 * 2048; bx -= 80; }
  int c0 = bx * 32, r0 = blockIdx.y * 32;
  int t = threadIdx.x;
  int r = t >> 3, c4 = (t & 7) * 4;
  float4 v = *(const float4*)(src + (size_t)(r0 + r) * C + c0 + c4);
  tile[r][c4] = v.x; tile[r][c4 + 1] = v.y; tile[r][c4 + 2] = v.z; tile[r][c4 + 3] = v.w;
  __syncthreads();
  int cc = t >> 3, r4 = (t & 7) * 4;
  bf16x4_t o;
  o[0] = (bf16)tile[r4][cc];     o[1] = (bf16)tile[r4 + 1][cc];
  o[2] = (bf16)tile[r4 + 2][cc]; o[3] = (bf16)tile[r4 + 3][cc];
  *(bf16x4_t*)(d0 + (size_t)(c0 + cc) * 2048 + r0 + r4) = o;
}

// ---------------- fp32 [R][C] -> bf16 [C][dstStride] transpose (wo) --------
__global__ __launch_bounds__(256) void wtrans_kernel(
    const float* __restrict__ src, bf16* __restrict__ dst, int C, int dstStride) {
  __shared__ float tile[32][33];
  int c0 = blockIdx.x * 32, r0 = blockIdx.y * 32;
  int t = threadIdx.x;
  int r = t >> 3, c4 = (t & 7) * 4;
  float4 v = *(const float4*)(src + (size_t)(r0 + r) * C + c0 + c4);
  tile[r][c4] = v.x; tile[r][c4 + 1] = v.y; tile[r][c4 + 2] = v.z; tile[r][c4 + 3] = v.w;
  __syncthreads();
  int cc = t >> 3, r4 = (t & 7) * 4;
  bf16x4_t o;
  o[0] = (bf16)tile[r4][cc];     o[1] = (bf16)tile[r4 + 1][cc];
  o[2] = (bf16)tile[r4 + 2][cc]; o[3] = (bf16)tile[r4 + 3][cc];
  *(bf16x4_t*)(dst + (size_t)(c0 + cc) * dstStride + r0 + r4) = o;
}

// ---------------- QKV GEMM (bf16 x bf16) + RoPE/scatter epilogue -----------
// XCD-swizzled: hw slot (x-major, xcd = slot&7) -> logical tile chunked so
// each XCD owns 96 contiguous logical tiles = 4 A-panel rows (2MB, L2-fit).
__global__ __launch_bounds__(256, 2) void qkv_gemm_rope(
    const bf16* __restrict__ A, const bf16* __restrict__ Bt,
    bf16* __restrict__ q_r, bf16* __restrict__ k_r, bf16* __restrict__ v_t,
    const float2* __restrict__ rope) {
  __shared__ char smem[32768];
  char* As = smem;
  char* Bs = smem + 16384;
  const int tid  = threadIdx.x;
  const int wid  = tid >> 6;
  const int lane = tid & 63;
  const int l15  = lane & 15;
  const int quad = lane >> 4;
  const int wm = wid >> 1, wn = wid & 1;

  const int slot = blockIdx.y * 24 + blockIdx.x;     // 0..767, hw dispatch order
  const int logical = (slot & 7) * 96 + (slot >> 3); // XCD-contiguous chunks
  const int bxl = logical % 24;
  const int byl = logical / 24;
  const int bm = byl * 128;
  const int bn = bxl * 128;
  const int K = 2048;

  f32x4_t acc[4][4] = {};

  for (int k0 = 0; k0 < K; k0 += 64) {
#pragma unroll
    for (int it = 0; it < 4; ++it) {
      int p = it * 256 + tid;
      int row = p >> 3;
      int j = (p & 7) ^ (row & 7);
      async_copy16(A + (size_t)(bm + row) * K + k0 + j * 8,
                   As + (size_t)(it * 256 + wid * 64) * 16);
      async_copy16(Bt + (size_t)(bn + row) * K + k0 + j * 8,
                   Bs + (size_t)(it * 256 + wid * 64) * 16);
    }
    __syncthreads();
#pragma unroll
    for (int kk = 0; kk < 64; kk += 32) {
      bf16x8_t af[4], bfr[4];
      int cbase = (kk >> 3) + quad;
#pragma unroll
      for (int mt = 0; mt < 4; ++mt) {
        int row = wm * 64 + mt * 16 + l15;
        af[mt] = *(const bf16x8_t*)(As + (size_t)(row * 8 + (cbase ^ (row & 7))) * 16);
      }
#pragma unroll
      for (int nt = 0; nt < 4; ++nt) {
        int row = wn * 64 + nt * 16 + l15;
        bfr[nt] = *(const bf16x8_t*)(Bs + (size_t)(row * 8 + (cbase ^ (row & 7))) * 16);
      }
#pragma unroll
      for (int mt = 0; mt < 4; ++mt)
#pragma unroll
        for (int nt = 0; nt < 4; ++nt)
          acc[mt][nt] = __builtin_amdgcn_mfma_f32_16x16x32_bf16(
              af[mt], bfr[nt], acc[mt][nt], 0, 0, 0);
    }
    __syncthreads();
  }

  const int cb = bxl * 2 + wn;
  const int rowbase = bm + wm * 64;
  const int bidx = bm >> 11;
  const float SC = 0.18033688011112043f; // 0.125 * log2(e), folded into Q

  if (cb < 40) {
    const bool isQ = (cb < 32);
    const float sc = isQ ? SC : 1.0f;
    bf16* base = isQ ? (q_r + (size_t)(bidx * NH + cb) * S_LEN * HD)
                     : (k_r + (size_t)(bidx * KVH + (cb - 32)) * S_LEN * HD);
#pragma unroll
    for (int nt = 0; nt < 2; ++nt) {
      int i = nt * 16 + l15;
#pragma unroll
      for (int mt = 0; mt < 4; ++mt)
#pragma unroll
        for (int r = 0; r < 4; ++r) {
          int row = rowbase + mt * 16 + quad * 4 + r;
          int s = row & 2047;
          float2 cs = rope[s * 32 + i];
          float x1 = acc[mt][nt][r], x2 = acc[mt][nt + 2][r];
          bf16* d = base + (size_t)s * HD;
          d[i]      = (bf16)((x1 * cs.x - x2 * cs.y) * sc);
          d[i + 32] = (bf16)((x2 * cs.x + x1 * cs.y) * sc);
        }
    }
  } else {
    const int kvh = cb - 40;
    bf16* base = v_t + (size_t)(bidx * KVH + kvh) * HD * S_LEN;
#pragma unroll
    for (int nt = 0; nt < 4; ++nt) {
      int d = nt * 16 + l15;
#pragma unroll
      for (int mt = 0; mt < 4; ++mt) {
        int s0 = (rowbase + mt * 16 + quad * 4) & 2047;
        bf16x4_t o;
        o[0] = (bf16)acc[mt][nt][0]; o[1] = (bf16)acc[mt][nt][1];
        o[2] = (bf16)acc[mt][nt][2]; o[3] = (bf16)acc[mt][nt][3];
        *(bf16x4_t*)(base + (size_t)d * S_LEN + s0) = o;
      }
    }
  }
}

// ---------------- bf16 GEMM: C[M][N] = A[M][K] * Bt[N][K]^T ----------------
// XCD-swizzled like qkv_gemm (grid 16x32 = 512 = 64/XCD contiguous).
template <typename OutT>
__global__ __launch_bounds__(256, 2) void gemm_bt(
    const bf16* __restrict__ A, const bf16* __restrict__ Bt,
    OutT* __restrict__ C, int N, int K) {
  __shared__ char smem[32768];
  char* As = smem;
  char* Bs = smem + 16384;
  const int tid  = threadIdx.x;
  const int wid  = tid >> 6;
  const int lane = tid & 63;
  const int l15  = lane & 15;
  const int quad = lane >> 4;
  const int wm = wid >> 1, wn = wid & 1;

  const int slot = blockIdx.y * 16 + blockIdx.x;     // 0..511, hw dispatch order
  const int logical = (slot & 7) * 64 + (slot >> 3); // XCD-contiguous chunks
  const int bm = (logical / 16) * 128;
  const int bn = (logical % 16) * 128;

  f32x4_t acc[4][4] = {};

  for (int k0 = 0; k0 < K; k0 += 64) {
#pragma unroll
    for (int it = 0; it < 4; ++it) {
      int p = it * 256 + tid;
      int row = p >> 3;
      int j = (p & 7) ^ (row & 7);
      async_copy16(A + (size_t)(bm + row) * K + k0 + j * 8,
                   As + (size_t)(it * 256 + wid * 64) * 16);
      async_copy16(Bt + (size_t)(bn + row) * K + k0 + j * 8,
                   Bs + (size_t)(it * 256 + wid * 64) * 16);
    }
    __syncthreads();
#pragma unroll
    for (int kk = 0; kk < 64; kk += 32) {
      bf16x8_t af[4], bfr[4];
      int cbase = (kk >> 3) + quad;
#pragma unroll
      for (int mt = 0; mt < 4; ++mt) {
        int row = wm * 64 + mt * 16 + l15;
        af[mt] = *(const bf16x8_t*)(As + (size_t)(row * 8 + (cbase ^ (row & 7))) * 16);
      }
#pragma unroll
      for (int nt = 0; nt < 4; ++nt) {
        int row = wn * 64 + nt * 16 + l15;
        bfr[nt] = *(const bf16x8_t*)(Bs + (size_t)(row * 8 + (cbase ^ (row & 7))) * 16);
      }
#pragma unroll
      for (int mt = 0; mt < 4; ++mt)
#pragma unroll
        for (int nt = 0; nt < 4; ++nt)
          acc[mt][nt] = __builtin_amdgcn_mfma_f32_16x16x32_bf16(
              af[mt], bfr[nt], acc[mt][nt], 0, 0, 0);
    }
    __syncthreads();
  }
#pragma unroll
  for (int mt = 0; mt < 4; ++mt)
#pragma unroll
    for (int nt = 0; nt < 4; ++nt)
#pragma unroll
      for (int r = 0; r < 4; ++r) {
        int row = bm + wm * 64 + mt * 16 + quad * 4 + r;
        int col = bn + wn * 64 + nt * 16 + l15;
        C[(size_t)row * N + col] = (OutT)acc[mt][nt][r];
      }
}

// ---------------- flash attention (GQA-shared, in-register P) --------------
// R8-frozen. Block = 8 waves (512 thr) = 4 q-heads x 2 q-subtiles of one KV
// group; each wave: 16 queries. Grid (S/32=64, B*KVH=16) = 1024 blocks.
// XCD-remapped: lin&7 owns KV groups {2*xcd, 2*xcd+1}.
// Barrier schedule: B1 drains K(kt); V(kt) DMA overlaps S+softmax; B2 drains
// V(kt); K(kt+1) DMA overlaps PV.
__global__ __launch_bounds__(512, 4) void attn_kernel(
    const bf16* __restrict__ q_r, const bf16* __restrict__ k_r,
    const bf16* __restrict__ v_t, bf16* __restrict__ attn) {
  __shared__ char smem[32768];
  char* Ks = smem;            // [key128][dim64], 3-bit row swizzle, 16KB
  char* Vs = smem + 16384;    // [dim64][key128], 4-bit row swizzle, 16KB
  const int tid = threadIdx.x;          // 0..511
  const int wid = tid >> 6;             // 0..7
  const int lane = tid & 63;
  const int l15 = lane & 15, quad = lane >> 4;

  const int lin = blockIdx.x + (blockIdx.y << 6);
  const int xcd = lin & 7;
  const int w = lin >> 3;                 // 0..127 within XCD
  const int blky = xcd * 2 + (w >> 6);    // b*KVH + kvh (2 groups per XCD)
  const int q0 = (w & 63) * 32 + (wid >> 2) * 16;

  const int b = blky >> 3, kvh = blky & 7;
  const int h = kvh * 4 + (wid & 3);      // this wave's q-head

  const bf16* Kg = k_r + (size_t)blky * S_LEN * HD;
  const bf16* Vg = v_t + (size_t)blky * HD * S_LEN;

  // Q fragments (B-operand: n=query=l15, k=dim=quad*8+j), pre-scaled.
  bf16x8_t qf0, qf1;
  {
    const bf16* qb = q_r + ((size_t)(b * NH + h) * S_LEN + q0 + l15) * HD;
    qf0 = *(const bf16x8_t*)(qb + quad * 8);
    qf1 = *(const bf16x8_t*)(qb + 32 + quad * 8);
  }
  bf16x8_t ones;
#pragma unroll
  for (int e = 0; e < 8; ++e) ones[e] = (bf16)1.0f;

  f32x4_t o_acc[4] = {};
  f32x4_t l_acc = {};

  // prologue: K(0) DMA (global source row bit2<->bit3 permuted)
#pragma unroll
  for (int it = 0; it < 2; ++it) {
    int p = it * 512 + tid;
    int row = p >> 3, j = (p & 7) ^ (row & 7);
    int gr = (row & ~12) | ((row & 4) << 1) | ((row & 8) >> 1);
    async_copy16(Kg + (size_t)gr * HD + j * 8,
                 Ks + (size_t)(it * 512 + wid * 64) * 16);
  }

  for (int kt = 0; kt < S_LEN / 128; ++kt) {
    __syncthreads();                     // B1: K(kt) landed; Vs free
#pragma unroll
    for (int it = 0; it < 2; ++it) {     // V(kt) DMA — overlaps S-phase
      int p = it * 512 + tid;
      int vrow = p >> 4, vj = (p & 15) ^ (vrow & 15);
      async_copy16(Vg + (size_t)vrow * S_LEN + kt * 128 + vj * 8,
                   Vs + (size_t)(it * 512 + wid * 64) * 16);
    }

    // S^T = K * Q^T for the 16-query tile; softmax+pack in registers.
    bf16x8_t pf[4];
    {
      f32x4_t sa[8];
#pragma unroll
      for (int t = 0; t < 8; ++t) sa[t] = f32x4_t{0.f, 0.f, 0.f, 0.f};
      __builtin_amdgcn_s_setprio(1);
#pragma unroll
      for (int t = 0; t < 8; ++t) {
        int row = t * 16 + l15;
        int s3 = l15 & 7;                // row&7 == l15&7 (16-aligned rows)
        bf16x8_t kf0 = *(const bf16x8_t*)(Ks + (size_t)(row * 8 + (quad ^ s3)) * 16);
        bf16x8_t kf1 = *(const bf16x8_t*)(Ks + (size_t)(row * 8 + ((4 + quad) ^ s3)) * 16);
        sa[t] = __builtin_amdgcn_mfma_f32_16x16x32_bf16(kf0, qf0, sa[t], 0, 0, 0);
        sa[t] = __builtin_amdgcn_mfma_f32_16x16x32_bf16(kf1, qf1, sa[t], 0, 0, 0);
      }
      __builtin_amdgcn_s_setprio(0);
      // exp2 + pack + permlane: build PV B-fragments in registers.
#pragma unroll
      for (int c = 0; c < 4; ++c) {
        u32 w0 = cvt_pk_bf16(__builtin_exp2f(sa[2 * c][0]),
                             __builtin_exp2f(sa[2 * c][1]));
        u32 w1 = cvt_pk_bf16(__builtin_exp2f(sa[2 * c][2]),
                             __builtin_exp2f(sa[2 * c][3]));
        u32 w2 = cvt_pk_bf16(__builtin_exp2f(sa[2 * c + 1][0]),
                             __builtin_exp2f(sa[2 * c + 1][1]));
        u32 w3 = cvt_pk_bf16(__builtin_exp2f(sa[2 * c + 1][2]),
                             __builtin_exp2f(sa[2 * c + 1][3]));
        permlane32_swap(w0, w2);         // w0 -> keys 8q'+{0,1}, w2 -> +{4,5}
        permlane32_swap(w1, w3);         // w1 -> keys 8q'+{2,3}, w3 -> +{6,7}
        u32x4_t pw;
        pw[0] = w0; pw[1] = w1; pw[2] = w2; pw[3] = w3;
        pf[c] = __builtin_bit_cast(bf16x8_t, pw);
      }
    }

    __syncthreads();                     // B2: V(kt) landed; Ks free

    if (kt < S_LEN / 128 - 1) {          // K(kt+1) DMA — overlaps PV
#pragma unroll
      for (int it = 0; it < 2; ++it) {
        int p = it * 512 + tid;
        int row = p >> 3, j = (p & 7) ^ (row & 7);
        int gr = (row & ~12) | ((row & 4) << 1) | ((row & 8) >> 1);
        async_copy16(Kg + (size_t)((kt + 1) * 128 + gr) * HD + j * 8,
                     Ks + (size_t)(it * 512 + wid * 64) * 16);
      }
    }

    // O^T += V^T * P^T ; l += ones * P^T (row-sum in matrix pipe).
    __builtin_amdgcn_s_setprio(1);
#pragma unroll
    for (int c = 0; c < 4; ++c) {
      l_acc = __builtin_amdgcn_mfma_f32_16x16x32_bf16(ones, pf[c], l_acc, 0, 0, 0);
#pragma unroll
      for (int nt = 0; nt < 4; ++nt) {
        int d = nt * 16 + l15;
        bf16x8_t vf = *(const bf16x8_t*)(Vs + d * 256 + (((4 * c + quad) ^ l15) * 16));
        o_acc[nt] = __builtin_amdgcn_mfma_f32_16x16x32_bf16(vf, pf[c], o_acc[nt], 0, 0, 0);
      }
    }
    __builtin_amdgcn_s_setprio(0);
  }

  __syncthreads();                       // all PV done; Ks+Vs reusable
  // finalize: every lane holds l for its query in l_acc[*] (all equal).
  char* Pw = smem + wid * 4096;          // 8 waves x 4KB spans Ks+Vs
  {
    float inv = 1.0f / l_acc[0];
    // O^T tile (cols=queries l15, rows=dims quad*4+r) -> Pw [16][72] transpose
#pragma unroll
    for (int nt = 0; nt < 4; ++nt) {
      bf16x4_t o;
      o[0] = (bf16)(o_acc[nt][0] * inv);
      o[1] = (bf16)(o_acc[nt][1] * inv);
      o[2] = (bf16)(o_acc[nt][2] * inv);
      o[3] = (bf16)(o_acc[nt][3] * inv);
      *(bf16x4_t*)(Pw + l15 * 144 + (nt * 16 + quad * 4) * 2) = o;
    }
    int row = lane >> 2, cc = lane & 3;
    bf16x8_t r0 = *(const bf16x8_t*)(Pw + row * 144 + cc * 32);
    bf16x8_t r1 = *(const bf16x8_t*)(Pw + row * 144 + cc * 32 + 16);
    int token = q0 + row;
    bf16* dst = attn + ((size_t)(b * S_LEN + token)) * HID + h * 64 + cc * 16;
    *(bf16x8_t*)dst = r0;
    *(bf16x8_t*)(dst + 8) = r1;
  }
}

// ---------------------------------------------------------------------------
extern "C" void kernel_launch(void* const* d_in, const int* in_sizes, int n_in,
                              void* d_out, int out_size, void* d_ws, size_t ws_size,
                              hipStream_t stream) {
  const float* x  = (const float*)d_in[0];
  const float* wq = (const float*)d_in[1];
  const float* wk = (const float*)d_in[2];
  const float* wv = (const float*)d_in[3];
  const float* wo = (const float*)d_in[4];
  float* out = (float*)d_out;
  char* ws = (char*)d_ws;

  // workspace layout (40 MiB, stream-ordered aliasing — proven):
  bf16* q_r    = (bf16*)(ws + 0);          // [0,16M)    QKV-epi .. attn
  bf16* k_r    = (bf16*)(ws + 16777216);   // [16M,20M)  QKV-epi .. attn
  bf16* v_t    = (bf16*)(ws + 20971520);   // [20M,24M)  QKV-epi .. attn
  bf16* wqkv_t = (bf16*)(ws + 25165824);   // [24M,36M)  dead after QKV GEMM
  bf16* attn   = (bf16*)(ws + 25165824);   // [24M,40M)  aliases wqkv_t
  bf16* wo_t   = (bf16*)(ws + 16777216);   // [16M,24M)  aliases k_r/v_t (after attn)
  float2* rope = (float2*)(ws + 37748736); // [36M,36.5M) written by cast, read by
                                           // qkv_gemm_rope, dead before attn writes
  bf16* x_b    = (bf16*)d_out;             // d_out as scratch (overwritten by O-GEMM)

  cast_bf16_kernel<<<8192, 256, 0, stream>>>(x, x_b, rope);
  wtrans3_kernel<<<dim3(96, 64), 256, 0, stream>>>(wq, wk, wv, wqkv_t);

  qkv_gemm_rope<<<dim3(24, 32), 256, 0, stream>>>(x_b, wqkv_t, q_r, k_r, v_t, rope);
  attn_kernel<<<dim3(64, 16), 512, 0, stream>>>(q_r, k_r, v_t, attn);

  wtrans_kernel<<<dim3(64, 64), 256, 0, stream>>>(wo, wo_t, 2048, 2048);
  gemm_bt<float><<<dim3(16, 32), 256, 0, stream>>>(attn, wo_t, out, 2048, 2048);
}